// Round 1
// baseline (34.384 us; speedup 1.0000x reference)
//
#include <hip/hip_runtime.h>

#define ALPHA 0.5

constexpr int BLK = 256;       // threads per block
constexpr int JCHUNK = 1024;   // j-elements staged in LDS per block

// Partial pairwise hinge sums. Grid: (n/BLK) x (n/JCHUNK).
// Each thread owns one i; block stages one j-chunk in LDS.
__global__ __launch_bounds__(BLK) void pair_partial_kernel(
    const float* __restrict__ logits,
    const float* __restrict__ labels,
    double* __restrict__ partial,   // [gridDim.x*gridDim.y][2] = {hinge_sum, count}
    int n)
{
    __shared__ float s_lab[JCHUNK];
    __shared__ float s_log[JCHUNK];
    __shared__ double s_red[BLK / 64][2];

    const int tid = threadIdx.x;
    const int i = blockIdx.x * BLK + tid;
    const int j0 = blockIdx.y * JCHUNK;
    const int jlen = min(JCHUNK, n - j0);

    for (int j = tid; j < jlen; j += BLK) {
        s_lab[j] = labels[j0 + j];
        s_log[j] = logits[j0 + j];
    }
    __syncthreads();

    float hsum = 0.0f;
    int cnt = 0;
    if (i < n) {
        const float yi = labels[i];
        const float li = logits[i];
#pragma unroll 8
        for (int j = 0; j < jlen; ++j) {
            const float yj = s_lab[j];
            const float lj = s_log[j];
            const float h = fmaxf(1.0f - (li - lj), 0.0f);
            const bool m = yi > yj;
            hsum += m ? h : 0.0f;
            cnt  += m ? 1 : 0;
        }
    }

    // wave64 butterfly reduce
    for (int off = 32; off > 0; off >>= 1) {
        hsum += __shfl_down(hsum, off, 64);
        cnt  += __shfl_down(cnt,  off, 64);
    }
    const int wave = tid >> 6;
    if ((tid & 63) == 0) {
        s_red[wave][0] = (double)hsum;
        s_red[wave][1] = (double)cnt;
    }
    __syncthreads();
    if (tid == 0) {
        double s = 0.0, c = 0.0;
        for (int w = 0; w < BLK / 64; ++w) { s += s_red[w][0]; c += s_red[w][1]; }
        const int b = blockIdx.y * gridDim.x + blockIdx.x;
        partial[2 * b]     = s;
        partial[2 * b + 1] = c;
    }
}

// One block: reduce partials + MSE, write scalar.
__global__ __launch_bounds__(BLK) void finalize_kernel(
    const float* __restrict__ logits,
    const float* __restrict__ labels,
    const double* __restrict__ partial,
    int nPartial, int n,
    float* __restrict__ out)
{
    __shared__ double s_s[BLK], s_c[BLK], s_m[BLK];
    const int tid = threadIdx.x;

    double s = 0.0, c = 0.0;
    for (int b = tid; b < nPartial; b += BLK) {
        s += partial[2 * b];
        c += partial[2 * b + 1];
    }
    double m = 0.0;
    for (int idx = tid; idx < n; idx += BLK) {
        const double d = (double)logits[idx] - (double)labels[idx];
        m += d * d;
    }
    s_s[tid] = s; s_c[tid] = c; s_m[tid] = m;
    __syncthreads();
    for (int off = BLK / 2; off > 0; off >>= 1) {
        if (tid < off) {
            s_s[tid] += s_s[tid + off];
            s_c[tid] += s_c[tid + off];
            s_m[tid] += s_m[tid + off];
        }
        __syncthreads();
    }
    if (tid == 0) {
        const double mse = s_m[0] / (double)n;
        const double ranking = (s_c[0] > 0.0) ? (s_s[0] / s_c[0]) : 0.0;
        out[0] = (float)(ALPHA * mse + (1.0 - ALPHA) * ranking);
    }
}

extern "C" void kernel_launch(void* const* d_in, const int* in_sizes, int n_in,
                              void* d_out, int out_size, void* d_ws, size_t ws_size,
                              hipStream_t stream) {
    const float* logits = (const float*)d_in[0];
    const float* labels = (const float*)d_in[1];
    const int n = in_sizes[0];

    const int gx = (n + BLK - 1) / BLK;        // 32 for n=8192
    const int gy = (n + JCHUNK - 1) / JCHUNK;  // 8  for n=8192
    double* partial = (double*)d_ws;           // needs gx*gy*2*8 bytes = 4 KB

    dim3 grid(gx, gy);
    pair_partial_kernel<<<grid, BLK, 0, stream>>>(logits, labels, partial, n);
    finalize_kernel<<<1, BLK, 0, stream>>>(logits, labels, partial, gx * gy, n,
                                           (float*)d_out);
}

// Round 2
// 23.258 us; speedup vs baseline: 1.4784x; 1.4784x over previous
//
#include <hip/hip_runtime.h>
#include <math.h>

#define ALPHA 0.5

constexpr int BLK = 256;      // threads per block
constexpr int IBLK = 4;       // i-values per thread (register tile)
constexpr int JCHUNK = 64;    // j-elements staged in LDS per block

// Partial pairwise hinge sums. Grid: (n/(BLK*IBLK)) x (n/JCHUNK).
__global__ __launch_bounds__(BLK) void pair_partial_kernel(
    const float* __restrict__ logits,
    const float* __restrict__ labels,
    double* __restrict__ partial,   // [nblocks][2] = {hinge_sum, count}
    int n)
{
    __shared__ float s_lab[JCHUNK];
    __shared__ float s_log[JCHUNK];
    __shared__ double s_red[BLK / 64][2];

    const int tid = threadIdx.x;
    const int ib = (blockIdx.x * BLK + tid) * IBLK;
    const int j0 = blockIdx.y * JCHUNK;
    const int jlen = min(JCHUNK, n - j0);

    for (int j = tid; j < jlen; j += BLK) {
        s_lab[j] = labels[j0 + j];
        s_log[j] = logits[j0 + j];
    }
    __syncthreads();

    float yi[IBLK], ai[IBLK], hsum[IBLK];
    int cnt[IBLK];
#pragma unroll
    for (int u = 0; u < IBLK; ++u) {
        const int i = ib + u;
        const bool v = i < n;
        // yi = -inf for inactive lanes -> mask never true -> zero contribution
        yi[u] = v ? labels[i] : -INFINITY;
        ai[u] = v ? (1.0f - logits[i]) : 0.0f;
        hsum[u] = 0.0f;
        cnt[u] = 0;
    }

    const int jlen4 = jlen >> 2;
    const float4* lab4 = reinterpret_cast<const float4*>(s_lab);
    const float4* log4 = reinterpret_cast<const float4*>(s_log);
#pragma unroll 2
    for (int jj = 0; jj < jlen4; ++jj) {
        const float4 yb = lab4[jj];
        const float4 lb = log4[jj];
#pragma unroll
        for (int c = 0; c < 4; ++c) {
            const float yj = (&yb.x)[c];
            const float lj = (&lb.x)[c];
#pragma unroll
            for (int u = 0; u < IBLK; ++u) {
                const float h = fmaxf(ai[u] + lj, 0.0f);  // relu(1 - (li - lj))
                const bool m = yi[u] > yj;
                hsum[u] += m ? h : 0.0f;
                cnt[u]  += m ? 1 : 0;
            }
        }
    }
    // scalar tail (not taken for n % JCHUNK == 0)
    for (int j = jlen4 << 2; j < jlen; ++j) {
        const float yj = s_lab[j];
        const float lj = s_log[j];
#pragma unroll
        for (int u = 0; u < IBLK; ++u) {
            const float h = fmaxf(ai[u] + lj, 0.0f);
            const bool m = yi[u] > yj;
            hsum[u] += m ? h : 0.0f;
            cnt[u]  += m ? 1 : 0;
        }
    }

    float hs = (hsum[0] + hsum[1]) + (hsum[2] + hsum[3]);
    int ct = (cnt[0] + cnt[1]) + (cnt[2] + cnt[3]);

    // wave64 butterfly reduce
    for (int off = 32; off > 0; off >>= 1) {
        hs += __shfl_down(hs, off, 64);
        ct += __shfl_down(ct, off, 64);
    }
    const int wave = tid >> 6;
    if ((tid & 63) == 0) {
        s_red[wave][0] = (double)hs;
        s_red[wave][1] = (double)ct;
    }
    __syncthreads();
    if (tid == 0) {
        double s = 0.0, c = 0.0;
        for (int w = 0; w < BLK / 64; ++w) { s += s_red[w][0]; c += s_red[w][1]; }
        const int b = blockIdx.y * gridDim.x + blockIdx.x;
        partial[2 * b]     = s;
        partial[2 * b + 1] = c;
    }
}

// One block: reduce partials + MSE, write scalar.
__global__ __launch_bounds__(BLK) void finalize_kernel(
    const float* __restrict__ logits,
    const float* __restrict__ labels,
    const double* __restrict__ partial,
    int nPartial, int n,
    float* __restrict__ out)
{
    __shared__ double s_s[BLK], s_c[BLK], s_m[BLK];
    const int tid = threadIdx.x;

    double s = 0.0, c = 0.0;
    for (int b = tid; b < nPartial; b += BLK) {
        s += partial[2 * b];
        c += partial[2 * b + 1];
    }
    double m = 0.0;
    for (int idx = tid; idx < n; idx += BLK) {
        const double d = (double)logits[idx] - (double)labels[idx];
        m += d * d;
    }
    s_s[tid] = s; s_c[tid] = c; s_m[tid] = m;
    __syncthreads();
    for (int off = BLK / 2; off > 0; off >>= 1) {
        if (tid < off) {
            s_s[tid] += s_s[tid + off];
            s_c[tid] += s_c[tid + off];
            s_m[tid] += s_m[tid + off];
        }
        __syncthreads();
    }
    if (tid == 0) {
        const double mse = s_m[0] / (double)n;
        const double ranking = (s_c[0] > 0.0) ? (s_s[0] / s_c[0]) : 0.0;
        out[0] = (float)(ALPHA * mse + (1.0 - ALPHA) * ranking);
    }
}

extern "C" void kernel_launch(void* const* d_in, const int* in_sizes, int n_in,
                              void* d_out, int out_size, void* d_ws, size_t ws_size,
                              hipStream_t stream) {
    const float* logits = (const float*)d_in[0];
    const float* labels = (const float*)d_in[1];
    const int n = in_sizes[0];

    const int gx = (n + BLK * IBLK - 1) / (BLK * IBLK);  // 8 for n=8192
    const int gy = (n + JCHUNK - 1) / JCHUNK;            // 128 for n=8192
    double* partial = (double*)d_ws;                     // gx*gy*2*8 B = 16 KB

    dim3 grid(gx, gy);
    pair_partial_kernel<<<grid, BLK, 0, stream>>>(logits, labels, partial, n);
    finalize_kernel<<<1, BLK, 0, stream>>>(logits, labels, partial, gx * gy, n,
                                           (float*)d_out);
}